// Round 1
// baseline (4880.129 us; speedup 1.0000x reference)
//
#include <hip/hip_runtime.h>
#include <math.h>

#define IN_DIM 20
#define DIM 128
#define HH 8
#define LL 3
#define BB 2
#define NP 192
#define DHH 16
#define C2 256
#define NN (NP*NP)
#define EPS 1e-5f

// ---------------- init: conv1d over seq for both x and c ----------------
// grid (NP, BB), block DIM
__global__ void k_conv_init(const float* __restrict__ seq, const float* __restrict__ w1,
                            const float* __restrict__ w2, float* __restrict__ X,
                            float* __restrict__ Cc) {
  int t = blockIdx.x, b = blockIdx.y, oc = threadIdx.x;
  __shared__ float ss[3][IN_DIM];
  if (threadIdx.x < 3*IN_DIM) {
    int k = threadIdx.x / IN_DIM, ic = threadIdx.x % IN_DIM;
    int tt = t + k - 1;
    ss[k][ic] = (tt >= 0 && tt < NP) ? seq[(b*NP + tt)*IN_DIM + ic] : 0.f;
  }
  __syncthreads();
  float a1 = 0.f, a2 = 0.f;
  #pragma unroll
  for (int ic = 0; ic < IN_DIM; ic++) {
    #pragma unroll
    for (int k = 0; k < 3; k++) {
      float sv = ss[k][ic];
      a1 = fmaf(w1[(oc*IN_DIM + ic)*3 + k], sv, a1);
      a2 = fmaf(w2[(oc*IN_DIM + ic)*3 + k], sv, a2);
    }
  }
  X[(b*NP + t)*DIM + oc] = a1;
  Cc[(b*DIM + oc)*NP + t] = a2;
}

// ---------------- c2 init / accumulate: seq2pair ----------------
template<bool INIT>
__global__ void k_seq2pair(const float* __restrict__ Cc, float* __restrict__ C2A) {
  int idx = blockIdx.x * 256 + threadIdx.x;
  int j = idx % NP;
  int i = (idx / NP) % NP;
  int ch = (idx / NN) % C2;
  int b = idx / (NN * C2);
  float add = (ch < DIM) ? Cc[(b*DIM + ch)*NP + i] : Cc[(b*DIM + (ch - DIM))*NP + j];
  if (INIT) C2A[idx] = add; else C2A[idx] += add;
}

// ---------------- conv1d + BN(train stats) + relu, fused ----------------
// grid DIM (one block per out channel), block NP (192)
__global__ void k_conv1d_bn_relu(const float* __restrict__ cin, const float* __restrict__ w,
                                 const float* __restrict__ g, const float* __restrict__ bb,
                                 float* __restrict__ cout) {
  int oc = blockIdx.x;
  int t = threadIdx.x;
  float raw[BB];
  for (int b = 0; b < BB; b++) {
    float acc = 0.f;
    for (int ic = 0; ic < DIM; ic++) {
      const float* cr = cin + (b*DIM + ic)*NP;
      const float* wr = w + (oc*DIM + ic)*3;
      float lf = (t > 0)      ? cr[t-1] : 0.f;
      float mf = cr[t];
      float rf = (t < NP-1)   ? cr[t+1] : 0.f;
      acc = fmaf(lf, wr[0], acc);
      acc = fmaf(mf, wr[1], acc);
      acc = fmaf(rf, wr[2], acc);
    }
    raw[b] = acc;
  }
  __shared__ float sb[NP];
  sb[t] = raw[0] + raw[1];
  __syncthreads();
  for (int s = 128; s > 0; s >>= 1) {
    if (t < s && t + s < NP) sb[t] += sb[t + s];
    __syncthreads();
  }
  float mean = sb[0] / (float)(BB*NP);
  __syncthreads();
  sb[t] = raw[0]*raw[0] + raw[1]*raw[1];
  __syncthreads();
  for (int s = 128; s > 0; s >>= 1) {
    if (t < s && t + s < NP) sb[t] += sb[t + s];
    __syncthreads();
  }
  float var = sb[0] / (float)(BB*NP) - mean*mean;
  float rstd = rsqrtf(var + EPS);
  float gg = g[oc], bo = bb[oc];
  for (int b = 0; b < BB; b++)
    cout[(b*DIM + oc)*NP + t] = fmaxf((raw[b] - mean)*rstd*gg + bo, 0.f);
}

// ---------------- x = LN(x + c^T) ----------------
// grid (NP, BB), block DIM
__global__ void k_add_ln(float* __restrict__ X, const float* __restrict__ cc,
                         const float* __restrict__ g, const float* __restrict__ bb) {
  int t = blockIdx.x, b = blockIdx.y, d = threadIdx.x;
  float v = X[(b*NP + t)*DIM + d] + cc[(b*DIM + d)*NP + t];
  __shared__ float sb[DIM];
  sb[d] = v; __syncthreads();
  for (int s = 64; s > 0; s >>= 1) { if (d < s) sb[d] += sb[d+s]; __syncthreads(); }
  float mean = sb[0] / (float)DIM;
  __syncthreads();
  float dv = v - mean;
  sb[d] = dv*dv; __syncthreads();
  for (int s = 64; s > 0; s >>= 1) { if (d < s) sb[d] += sb[d+s]; __syncthreads(); }
  float var = sb[0] / (float)DIM;
  float rstd = rsqrtf(var + EPS);
  X[(b*NP + t)*DIM + d] = dv * rstd * g[d] + bb[d];
}

// ---------------- conv2d weight transpose: [oc][ic][3][3] -> [ic][3*3][oc] ----------------
__global__ void k_wtrans(const float* __restrict__ w, float* __restrict__ wt) {
  int idx = blockIdx.x * 256 + threadIdx.x;      // C2*9*C2 total
  int oc = idx % C2;
  int kk = (idx / C2) % 9;
  int ic = idx / (C2*9);
  wt[idx] = w[(oc*C2 + ic)*9 + kk];
}

// ---------------- the heavy kernel: 3x3 conv2d, raw output ----------------
// grid (6 = 3 jtiles * 2 octiles, NP, BB), block 256
// block tile: 128 oc x 64 contiguous j in one row i; thread microtile 8 oc x 4 j
#define JT 64
#define OCT 128
#define ICC 4
__global__ __launch_bounds__(256) void k_conv2d(const float* __restrict__ in,
                                                const float* __restrict__ wt,
                                                float* __restrict__ out) {
  __shared__ float s_in[ICC*3][JT + 4];   // [ic*3+ki][c], c -> col (j0-1+c), 66 used
  __shared__ float s_w[ICC*9*OCT];        // [ic][ki*3+kj][oc]
  int jt  = blockIdx.x % 3;
  int oct = blockIdx.x / 3;
  int i = blockIdx.y;
  int b = blockIdx.z;
  int j0 = jt * JT;
  int oc0 = oct * OCT;
  int tid = threadIdx.x;
  int tj  = (tid & 15) * 4;
  int toc = (tid >> 4) * 8;
  float acc[8][4] = {};
  const float* inB = in + (size_t)b * C2 * NN;
  for (int ic0 = 0; ic0 < C2; ic0 += ICC) {
    __syncthreads();
    for (int l = tid; l < ICC*3*(JT+2); l += 256) {
      int c = l % (JT+2);
      int r = l / (JT+2);
      int ki = r % 3, ic = r / 3;
      int row = i + ki - 1;
      int col = j0 - 1 + c;
      float v = 0.f;
      if ((unsigned)row < NP && (unsigned)col < NP)
        v = inB[(size_t)(ic0+ic)*NN + row*NP + col];
      s_in[r][c] = v;
    }
    for (int l = tid; l < ICC*9*OCT; l += 256) {
      int oc_l = l & (OCT-1);
      int r = l >> 7;
      int kk = r % 9, ic_l = r / 9;
      s_w[l] = wt[((size_t)(ic0+ic_l)*9 + kk)*C2 + oc0 + oc_l];
    }
    __syncthreads();
    #pragma unroll
    for (int ic = 0; ic < ICC; ic++) {
      float iv[3][6];
      #pragma unroll
      for (int ki = 0; ki < 3; ki++) {
        const float* p = &s_in[ic*3 + ki][tj];
        #pragma unroll
        for (int u = 0; u < 6; u++) iv[ki][u] = p[u];
      }
      const float* wp = s_w + ic*9*OCT + toc;
      #pragma unroll
      for (int ki = 0; ki < 3; ki++) {
        #pragma unroll
        for (int kj = 0; kj < 3; kj++) {
          const float* wq = wp + (ki*3 + kj)*OCT;
          #pragma unroll
          for (int o = 0; o < 8; o++) {
            float wv = wq[o];
            #pragma unroll
            for (int jj = 0; jj < 4; jj++)
              acc[o][jj] = fmaf(wv, iv[ki][jj + kj], acc[o][jj]);
          }
        }
      }
    }
  }
  float* outB = out + (size_t)b * C2 * NN;
  #pragma unroll
  for (int o = 0; o < 8; o++) {
    float* po = outB + (size_t)(oc0 + toc + o)*NN + i*NP + j0 + tj;
    #pragma unroll
    for (int jj = 0; jj < 4; jj++) po[jj] = acc[o][jj];
  }
}

// ---------------- BN2 stats: one block per channel ----------------
__global__ void k_bn2_stats(const float* __restrict__ raw, float* __restrict__ stat) {
  int c = blockIdx.x, tid = threadIdx.x;
  float s = 0.f, s2 = 0.f;
  for (int b = 0; b < BB; b++) {
    const float* p = raw + (size_t)(b*C2 + c)*NN;
    for (int idx = tid; idx < NN; idx += 256) { float v = p[idx]; s += v; s2 = fmaf(v, v, s2); }
  }
  __shared__ float sb[256], sb2[256];
  sb[tid] = s; sb2[tid] = s2; __syncthreads();
  for (int st = 128; st > 0; st >>= 1) {
    if (tid < st) { sb[tid] += sb[tid+st]; sb2[tid] += sb2[tid+st]; }
    __syncthreads();
  }
  if (tid == 0) {
    float mean = sb[0] / (float)(BB*NN);
    float var  = sb2[0] / (float)(BB*NN) - mean*mean;
    stat[c] = mean;
    stat[C2 + c] = rsqrtf(var + EPS);
  }
}

// ---------------- BN2 normalize + relu -> new c2 state ----------------
__global__ void k_bn2_norm(const float* __restrict__ raw, const float* __restrict__ stat,
                           const float* __restrict__ g, const float* __restrict__ bb,
                           float* __restrict__ outc2) {
  int idx = blockIdx.x * 256 + threadIdx.x;
  int c = (idx / NN) % C2;
  outc2[idx] = fmaxf((raw[idx] - stat[c]) * stat[C2 + c] * g[c] + bb[c], 0.f);
}

// ---------------- gate projection: t[b,h,i,j] = sum_c c2[b,c,i,j]*wd[h,c] ----------------
// grid (NP, BB), block NP
__global__ void k_gate_proj(const float* __restrict__ c2, const float* __restrict__ wd,
                            float* __restrict__ tg) {
  int i = blockIdx.x, b = blockIdx.y, j = threadIdx.x;
  __shared__ float swd[HH*C2];
  for (int l = j; l < HH*C2; l += NP) swd[l] = wd[l];
  __syncthreads();
  float acc[HH] = {};
  const float* base = c2 + (size_t)b*C2*NN + (size_t)i*NP + j;
  for (int c = 0; c < C2; c++) {
    float v = base[(size_t)c*NN];
    #pragma unroll
    for (int h = 0; h < HH; h++) acc[h] = fmaf(v, swd[h*C2 + c], acc[h]);
  }
  for (int h = 0; h < HH; h++)
    tg[((size_t)(b*HH + h)*NP + i)*NP + j] = acc[h];
}

// ---------------- gate = sigmoid(t + t^T + bias) ----------------
// grid (NP, HH, BB), block NP
__global__ void k_gate_sym(const float* __restrict__ tg, const float* __restrict__ wdb,
                           float* __restrict__ gate) {
  int i = blockIdx.x, h = blockIdx.y, b = blockIdx.z, j = threadIdx.x;
  size_t bh = (size_t)(b*HH + h);
  float v = tg[(bh*NP + i)*NP + j] + tg[(bh*NP + j)*NP + i] + wdb[h];
  gate[(bh*NP + i)*NP + j] = 1.f / (1.f + expf(-v));
}

// ---------------- q,k,v = heads(relu(x @ w^T + b)) ----------------
// grid (NP, BB), block DIM
__global__ void k_qkv(const float* __restrict__ X,
                      const float* __restrict__ wq, const float* __restrict__ bq,
                      const float* __restrict__ wk, const float* __restrict__ bk,
                      const float* __restrict__ wv, const float* __restrict__ bv,
                      float* __restrict__ Q, float* __restrict__ K, float* __restrict__ V) {
  int t = blockIdx.x, b = blockIdx.y, d = threadIdx.x;
  __shared__ float sy[DIM];
  sy[d] = X[(b*NP + t)*DIM + d];
  __syncthreads();
  float aq = bq[d], ak = bk[d], av = bv[d];
  for (int e = 0; e < DIM; e++) {
    float xv = sy[e];
    aq = fmaf(wq[d*DIM + e], xv, aq);
    ak = fmaf(wk[d*DIM + e], xv, ak);
    av = fmaf(wv[d*DIM + e], xv, av);
  }
  int h = d >> 4, dh = d & 15;
  size_t o = ((size_t)(b*HH + h)*NP + t)*DHH + dh;
  Q[o] = fmaxf(aq, 0.f); K[o] = fmaxf(ak, 0.f); V[o] = fmaxf(av, 0.f);
}

// ---------------- attention row: scores, softmax(masked), *gate, upd ----------------
// grid (NP, HH, BB), block NP
__global__ void k_attn(const float* __restrict__ Q, const float* __restrict__ K,
                       const float* __restrict__ V, const float* __restrict__ gate,
                       const float* __restrict__ mask, float* __restrict__ upd) {
  int i = blockIdx.x, h = blockIdx.y, b = blockIdx.z, j = threadIdx.x;
  size_t bh = (size_t)(b*HH + h);
  __shared__ float sq[DHH];
  __shared__ float sb[NP];
  __shared__ float sattn[NP];
  if (j < DHH) sq[j] = Q[(bh*NP + i)*DHH + j];
  __syncthreads();
  const float* kr = K + (bh*NP + j)*DHH;
  float a = 0.f;
  #pragma unroll
  for (int d = 0; d < DHH; d++) a = fmaf(sq[d], kr[d], a);
  a *= 0.25f;   // 1/sqrt(16)
  sb[j] = a; __syncthreads();
  for (int s = 128; s > 0; s >>= 1) {
    if (j < s && j + s < NP) sb[j] = fmaxf(sb[j], sb[j+s]);
    __syncthreads();
  }
  float amax = sb[0];
  __syncthreads();
  float e = expf(a - amax) * mask[b*NP + j];
  sb[j] = e; __syncthreads();
  for (int s = 128; s > 0; s >>= 1) {
    if (j < s && j + s < NP) sb[j] += sb[j+s];
    __syncthreads();
  }
  float denom = sb[0] + 1e-6f;
  float attn = (e / denom) * gate[(bh*NP + i)*NP + j];
  sattn[j] = attn;
  __syncthreads();
  if (j < DHH) {
    float acc = 0.f;
    for (int jj = 0; jj < NP; jj++)
      acc = fmaf(sattn[jj], V[(bh*NP + jj)*DHH + j], acc);
    upd[((size_t)(b*NP) + i)*DIM + h*DHH + j] = acc;
  }
}

// ---------------- x = relu((x + upd) @ wl^T + bl) ----------------
// grid (NP, BB), block DIM
__global__ void k_xup(float* __restrict__ X, const float* __restrict__ upd,
                      const float* __restrict__ wl, const float* __restrict__ bl) {
  int t = blockIdx.x, b = blockIdx.y, d = threadIdx.x;
  __shared__ float sy[DIM];
  size_t o = (size_t)(b*NP + t)*DIM;
  sy[d] = X[o + d] + upd[o + d];
  __syncthreads();
  float acc = bl[d];
  for (int e = 0; e < DIM; e++) acc = fmaf(wl[d*DIM + e], sy[e], acc);
  X[o + d] = fmaxf(acc, 0.f);
}

// ---------------- out = relu(x @ fc^T + fb) ----------------
__global__ void k_final(const float* __restrict__ X, const float* __restrict__ fc,
                        const float* __restrict__ fb, float* __restrict__ out) {
  int t = blockIdx.x, b = blockIdx.y, d = threadIdx.x;
  __shared__ float sy[DIM];
  size_t o = (size_t)(b*NP + t)*DIM;
  sy[d] = X[o + d];
  __syncthreads();
  float acc = fb[d];
  for (int e = 0; e < DIM; e++) acc = fmaf(fc[d*DIM + e], sy[e], acc);
  out[o + d] = fmaxf(acc, 0.f);
}

extern "C" void kernel_launch(void* const* d_in, const int* in_sizes, int n_in,
                              void* d_out, int out_size, void* d_ws, size_t ws_size,
                              hipStream_t stream) {
  const float* seq     = (const float*)d_in[0];
  const float* mask    = (const float*)d_in[1];
  const float* conv1_w = (const float*)d_in[2];
  const float* conv2_w = (const float*)d_in[3];
  const float* ln_g    = (const float*)d_in[4];
  const float* ln_b    = (const float*)d_in[5];
  const float* c1d_w   = (const float*)d_in[6];
  const float* bn1_g   = (const float*)d_in[7];
  const float* bn1_b   = (const float*)d_in[8];
  const float* c2d_w   = (const float*)d_in[9];
  const float* bn2_g   = (const float*)d_in[10];
  const float* bn2_b   = (const float*)d_in[11];
  const float* wq_w    = (const float*)d_in[12];
  const float* wq_b    = (const float*)d_in[13];
  const float* wk_w    = (const float*)d_in[14];
  const float* wk_b    = (const float*)d_in[15];
  const float* wv_w    = (const float*)d_in[16];
  const float* wv_b    = (const float*)d_in[17];
  const float* wd_w    = (const float*)d_in[18];
  const float* wd_b    = (const float*)d_in[19];
  const float* wl_w    = (const float*)d_in[20];
  const float* wl_b    = (const float*)d_in[21];
  const float* fc_w    = (const float*)d_in[22];
  const float* fc_b    = (const float*)d_in[23];
  float* out = (float*)d_out;

  float* ws = (float*)d_ws;
  float* X    = ws; ws += BB*NP*DIM;
  float* Ca   = ws; ws += BB*DIM*NP;
  float* Cb   = ws; ws += BB*DIM*NP;
  float* Q    = ws; ws += BB*NP*DIM;
  float* K    = ws; ws += BB*NP*DIM;
  float* V    = ws; ws += BB*NP*DIM;
  float* UPD  = ws; ws += BB*NP*DIM;
  float* TG   = ws; ws += (size_t)BB*HH*NN;
  float* GATE = ws; ws += (size_t)BB*HH*NN;
  float* WT   = ws; ws += C2*C2*9;
  float* STAT = ws; ws += 2*C2;
  float* C2A  = ws; ws += (size_t)BB*C2*NN;
  float* C2B  = ws; ws += (size_t)BB*C2*NN;

  k_conv_init<<<dim3(NP, BB), DIM, 0, stream>>>(seq, conv1_w, conv2_w, X, Ca);
  k_seq2pair<true><<<(BB*C2*NN)/256, 256, 0, stream>>>(Ca, C2A);

  const float* cin = Ca;
  float* cout = Cb;
  for (int l = 0; l < LL; l++) {
    k_conv1d_bn_relu<<<DIM, NP, 0, stream>>>(cin, c1d_w + (size_t)l*DIM*DIM*3,
                                             bn1_g + l*DIM, bn1_b + l*DIM, cout);
    k_add_ln<<<dim3(NP, BB), DIM, 0, stream>>>(X, cout, ln_g + l*DIM, ln_b + l*DIM);
    k_seq2pair<false><<<(BB*C2*NN)/256, 256, 0, stream>>>(cout, C2A);
    k_wtrans<<<(C2*C2*9)/256, 256, 0, stream>>>(c2d_w + (size_t)l*C2*C2*9, WT);
    k_conv2d<<<dim3(6, NP, BB), 256, 0, stream>>>(C2A, WT, C2B);
    k_bn2_stats<<<C2, 256, 0, stream>>>(C2B, STAT);
    k_bn2_norm<<<(BB*C2*NN)/256, 256, 0, stream>>>(C2B, STAT, bn2_g + l*C2, bn2_b + l*C2, C2A);
    k_gate_proj<<<dim3(NP, BB), NP, 0, stream>>>(C2A, wd_w + (size_t)l*HH*C2, TG);
    k_gate_sym<<<dim3(NP, HH, BB), NP, 0, stream>>>(TG, wd_b + l*HH, GATE);
    k_qkv<<<dim3(NP, BB), DIM, 0, stream>>>(X, wq_w + (size_t)l*DIM*DIM, wq_b + l*DIM,
                                            wk_w + (size_t)l*DIM*DIM, wk_b + l*DIM,
                                            wv_w + (size_t)l*DIM*DIM, wv_b + l*DIM, Q, K, V);
    k_attn<<<dim3(NP, HH, BB), NP, 0, stream>>>(Q, K, V, GATE, mask, UPD);
    k_xup<<<dim3(NP, BB), DIM, 0, stream>>>(X, UPD, wl_w + (size_t)l*DIM*DIM, wl_b + l*DIM);
    float* tmp = (float*)cin; cin = cout; cout = tmp;
  }
  k_final<<<dim3(NP, BB), DIM, 0, stream>>>(X, fc_w, fc_b, out);
}

// Round 2
// 1009.707 us; speedup vs baseline: 4.8332x; 4.8332x over previous
//
#include <hip/hip_runtime.h>
#include <math.h>

#define IN_DIM 20
#define DIM 128
#define HH 8
#define LL 3
#define BB 2
#define NP 192
#define DHH 16
#define C2 256
#define NN (NP*NP)
#define EPS 1e-5f

typedef __bf16 bf16x8 __attribute__((ext_vector_type(8)));
typedef float  f32x16 __attribute__((ext_vector_type(16)));

union Pack8 { __bf16 h[8]; uint4 u; };

// ---------------- init: conv1d over seq for both x and c ----------------
__global__ void k_conv_init(const float* __restrict__ seq, const float* __restrict__ w1,
                            const float* __restrict__ w2, float* __restrict__ X,
                            float* __restrict__ Cc) {
  int t = blockIdx.x, b = blockIdx.y, oc = threadIdx.x;
  __shared__ float ss[3][IN_DIM];
  if (threadIdx.x < 3*IN_DIM) {
    int k = threadIdx.x / IN_DIM, ic = threadIdx.x % IN_DIM;
    int tt = t + k - 1;
    ss[k][ic] = (tt >= 0 && tt < NP) ? seq[(b*NP + tt)*IN_DIM + ic] : 0.f;
  }
  __syncthreads();
  float a1 = 0.f, a2 = 0.f;
  #pragma unroll
  for (int ic = 0; ic < IN_DIM; ic++) {
    #pragma unroll
    for (int k = 0; k < 3; k++) {
      float sv = ss[k][ic];
      a1 = fmaf(w1[(oc*IN_DIM + ic)*3 + k], sv, a1);
      a2 = fmaf(w2[(oc*IN_DIM + ic)*3 + k], sv, a2);
    }
  }
  X[(b*NP + t)*DIM + oc] = a1;
  Cc[(b*DIM + oc)*NP + t] = a2;
}

// ---------------- conv1d + BN(train stats) + relu, fused ----------------
__global__ void k_conv1d_bn_relu(const float* __restrict__ cin, const float* __restrict__ w,
                                 const float* __restrict__ g, const float* __restrict__ bb,
                                 float* __restrict__ cout) {
  int oc = blockIdx.x;
  int t = threadIdx.x;
  float raw[BB];
  for (int b = 0; b < BB; b++) {
    float acc = 0.f;
    for (int ic = 0; ic < DIM; ic++) {
      const float* cr = cin + (b*DIM + ic)*NP;
      const float* wr = w + (oc*DIM + ic)*3;
      float lf = (t > 0)      ? cr[t-1] : 0.f;
      float mf = cr[t];
      float rf = (t < NP-1)   ? cr[t+1] : 0.f;
      acc = fmaf(lf, wr[0], acc);
      acc = fmaf(mf, wr[1], acc);
      acc = fmaf(rf, wr[2], acc);
    }
    raw[b] = acc;
  }
  __shared__ float sb[NP];
  sb[t] = raw[0] + raw[1];
  __syncthreads();
  for (int s = 128; s > 0; s >>= 1) {
    if (t < s && t + s < NP) sb[t] += sb[t + s];
    __syncthreads();
  }
  float mean = sb[0] / (float)(BB*NP);
  __syncthreads();
  sb[t] = raw[0]*raw[0] + raw[1]*raw[1];
  __syncthreads();
  for (int s = 128; s > 0; s >>= 1) {
    if (t < s && t + s < NP) sb[t] += sb[t + s];
    __syncthreads();
  }
  float var = sb[0] / (float)(BB*NP) - mean*mean;
  float rstd = rsqrtf(var + EPS);
  float gg = g[oc], bo = bb[oc];
  for (int b = 0; b < BB; b++)
    cout[(b*DIM + oc)*NP + t] = fmaxf((raw[b] - mean)*rstd*gg + bo, 0.f);
}

// ---------------- x = LN(x + c^T) ----------------
__global__ void k_add_ln(float* __restrict__ X, const float* __restrict__ cc,
                         const float* __restrict__ g, const float* __restrict__ bb) {
  int t = blockIdx.x, b = blockIdx.y, d = threadIdx.x;
  float v = X[(b*NP + t)*DIM + d] + cc[(b*DIM + d)*NP + t];
  __shared__ float sb[DIM];
  sb[d] = v; __syncthreads();
  for (int s = 64; s > 0; s >>= 1) { if (d < s) sb[d] += sb[d+s]; __syncthreads(); }
  float mean = sb[0] / (float)DIM;
  __syncthreads();
  float dv = v - mean;
  sb[d] = dv*dv; __syncthreads();
  for (int s = 64; s > 0; s >>= 1) { if (d < s) sb[d] += sb[d+s]; __syncthreads(); }
  float var = sb[0] / (float)DIM;
  float rstd = rsqrtf(var + EPS);
  X[(b*NP + t)*DIM + d] = dv * rstd * g[d] + bb[d];
}

// ---------------- conv2d weight prep: fp32 [L][oc][ic][3][3] -> bf16 [L][chunk16][kk9][kh2][oc256][8] ----------------
__global__ void k_wprep(const float* __restrict__ w, __bf16* __restrict__ wtb) {
  int blk = blockIdx.x;            // 3*16*9
  int kk = blk % 9;
  int chunk = (blk / 9) % 16;
  int l = blk / (9*16);
  int kh = threadIdx.x >> 8;
  int oc = threadIdx.x & 255;
  Pack8 p;
  #pragma unroll
  for (int e = 0; e < 8; e++) {
    int ic = chunk*16 + kh*8 + e;
    p.h[e] = (__bf16)w[(((size_t)(l*C2 + oc))*C2 + ic)*9 + kk];
  }
  size_t unit = ((((size_t)(l*16 + chunk)*9 + kk)*2 + kh)*256 + oc);
  ((uint4*)wtb)[unit] = p.u;
}

// ---------------- layer-0 conv input build: bf16(seq2pair(Cc) + seq2pair(CL0)) ----------------
// also zeroes STAT2
__global__ void k_make_convin(const float* __restrict__ Cc, const float* __restrict__ CL0,
                              __bf16* __restrict__ inb, float* __restrict__ STAT2) {
  int idx = blockIdx.x*256 + threadIdx.x;   // (b,chunk,i,kh,j) units
  if (blockIdx.x == 0 && threadIdx.x < 256) {
    STAT2[threadIdx.x] = 0.f; STAT2[256 + threadIdx.x] = 0.f;
  }
  int j = idx % 192;
  int r1 = idx / 192;
  int kh = r1 & 1;
  int r2 = r1 >> 1;
  int i = r2 % 192;
  int r3 = r2 / 192;
  int chunk = r3 % 16;
  int b = r3 / 16;
  Pack8 p;
  #pragma unroll
  for (int e = 0; e < 8; e++) {
    int c = chunk*16 + kh*8 + e;
    float v;
    if (c < DIM) v = Cc[(b*DIM + c)*NP + i] + CL0[(b*DIM + c)*NP + i];
    else { int cc = c - DIM; v = Cc[(b*DIM + cc)*NP + j] + CL0[(b*DIM + cc)*NP + j]; }
    p.h[e] = (__bf16)v;
  }
  ((uint4*)inb)[idx] = p.u;
}

// ---------------- the heavy kernel: implicit-GEMM bf16 MFMA 3x3 conv ----------------
// grid (3 jt, 48 it, 4 = b*2+oct), block 256 (4 waves)
// block tile 128 oc x (4 rows x 64 cols); wave tile 64 oc x (2 rows x 64 cols)
// K loop: 16 chunks of 16 ic x 9 kernel positions; mfma_f32_32x32x16_bf16
__global__ __launch_bounds__(256, 2)
void k_conv2d_mfma(const __bf16* __restrict__ inb,   // [b][16][192][2][192][8]
                   const __bf16* __restrict__ wtb,   // [16][9][2][256][8] (layer slice)
                   float* __restrict__ out) {        // [b][256][192][192] raw
  __shared__ __align__(16) __bf16 sW[9*2*128*8];     // [kk][kh][oc128][8]
  __shared__ __align__(16) __bf16 sI[6*2*80*8];      // [r6][kh][c80][8]
  int tid = threadIdx.x;
  int jt = blockIdx.x, it = blockIdx.y, zz = blockIdx.z;
  int b = zz >> 1, oct = zz & 1;
  int i0 = it*4, j0 = jt*64, oc0 = oct*128;
  int lane = tid & 63, wv = tid >> 6;
  int wm = wv & 1, wn = wv >> 1;
  int ln31 = lane & 31, kh = lane >> 5;

  const uint4* gW = (const uint4*)wtb;
  const uint4* gI = (const uint4*)inb;
  uint4* lW = (uint4*)sW;
  uint4* lI = (uint4*)sI;

  f32x16 acc[2][4];
  #pragma unroll
  for (int m = 0; m < 2; m++)
    #pragma unroll
    for (int n = 0; n < 4; n++)
      #pragma unroll
      for (int q = 0; q < 16; q++) acc[m][n][q] = 0.f;

  uint4 wreg[9], ireg[4];

  auto load_w = [&](int chunk) {
    #pragma unroll
    for (int t = 0; t < 9; t++) {
      int u = t*256 + tid;                 // 0..2303
      int kkh = u >> 7, oc_l = u & 127;
      wreg[t] = gW[((size_t)chunk*18 + kkh)*256 + oc0 + oc_l];
    }
  };
  auto load_i = [&](int chunk) {
    #pragma unroll
    for (int t = 0; t < 4; t++) {
      int u = t*256 + tid;                 // 0..959 used
      uint4 v; v.x = v.y = v.z = v.w = 0u;
      if (u < 960) {
        int r = u / 160, rem = u % 160;
        int khu = rem / 80, cc = rem % 80;
        int row = i0 - 1 + r;
        int cj = j0 - 8 + cc;
        if ((unsigned)row < 192u && (unsigned)cj < 192u)
          v = gI[(((size_t)(b*16 + chunk)*192 + row)*2 + khu)*192 + cj];
      }
      ireg[t] = v;
    }
  };

  load_w(0); load_i(0);

  for (int chunk = 0; chunk < 16; ++chunk) {
    if (chunk) __syncthreads();            // prev LDS reads done
    #pragma unroll
    for (int t = 0; t < 9; t++) lW[t*256 + tid] = wreg[t];
    #pragma unroll
    for (int t = 0; t < 4; t++) {
      int u = t*256 + tid;
      if (u < 960) {
        int r = u / 160, rem = u % 160;
        int khu = rem / 80, cc = rem % 80;
        lI[(r*2 + khu)*80 + cc] = ireg[t];
      }
    }
    if (chunk < 15) { load_w(chunk+1); load_i(chunk+1); }   // prefetch next
    __syncthreads();

    #pragma unroll
    for (int kk = 0; kk < 9; kk++) {
      const int ki = kk/3, kj = kk%3;
      bf16x8 a0 = *(const bf16x8*)(sW + (((kk*2 + kh)*128) + wm*64 +      ln31)*8);
      bf16x8 a1 = *(const bf16x8*)(sW + (((kk*2 + kh)*128) + wm*64 + 32 + ln31)*8);
      #pragma unroll
      for (int nt = 0; nt < 4; nt++) {
        int r  = wn*2 + (nt>>1) + ki;
        int cc = (nt&1)*32 + ln31 + kj + 7;
        bf16x8 bv = *(const bf16x8*)(sI + ((r*2 + kh)*80 + cc)*8);
        acc[0][nt] = __builtin_amdgcn_mfma_f32_32x32x16_bf16(a0, bv, acc[0][nt], 0, 0, 0);
        acc[1][nt] = __builtin_amdgcn_mfma_f32_32x32x16_bf16(a1, bv, acc[1][nt], 0, 0, 0);
      }
    }
  }

  // epilogue: C/D layout col=lane&31 (pixel), row=(reg&3)+8*(reg>>2)+4*(lane>>5) (oc)
  #pragma unroll
  for (int mt = 0; mt < 2; mt++) {
    int ocb = oc0 + wm*64 + mt*32;
    #pragma unroll
    for (int nt = 0; nt < 4; nt++) {
      int ii = i0 + wn*2 + (nt>>1);
      int jj = j0 + (nt&1)*32 + ln31;
      #pragma unroll
      for (int reg = 0; reg < 16; reg++) {
        int row = (reg & 3) + 8*(reg >> 2) + 4*kh;
        out[((size_t)(b*C2 + ocb + row))*NN + ii*NP + jj] = acc[mt][nt][reg];
      }
    }
  }
}

// ---------------- BN2 stats partials: grid (C2, 4), atomics into STAT2 ----------------
__global__ void k_bn2_stats4(const float* __restrict__ raw, float* __restrict__ STAT2) {
  int c = blockIdx.x, q = blockIdx.y, tid = threadIdx.x;
  float s = 0.f, s2 = 0.f;
  for (int b = 0; b < BB; b++) {
    const float* p = raw + ((size_t)(b*C2 + c))*NN + q*(NN/4);
    for (int idx = tid; idx < NN/4; idx += 256) { float v = p[idx]; s += v; s2 = fmaf(v, v, s2); }
  }
  __shared__ float sb[256], sb2[256];
  sb[tid] = s; sb2[tid] = s2; __syncthreads();
  for (int st = 128; st > 0; st >>= 1) {
    if (tid < st) { sb[tid] += sb[tid+st]; sb2[tid] += sb2[tid+st]; }
    __syncthreads();
  }
  if (tid == 0) {
    atomicAdd(&STAT2[c], sb[0]);
    atomicAdd(&STAT2[C2 + c], sb2[0]);
  }
}

// ---------------- fused: BN2 norm+relu -> state, gate projection, next conv input bf16 ----------------
// grid (192, 2), block 192. WRITE_NEXT: also emit bf16 conv input for next layer (state + seq2pair(CLn))
template<int WRITE_NEXT>
__global__ void k_bn2_norm_gate(const float* __restrict__ raw, const float* __restrict__ STAT2,
                                const float* __restrict__ g, const float* __restrict__ bb,
                                const float* __restrict__ wd, const float* __restrict__ CLn,
                                __bf16* __restrict__ inb_next, float* __restrict__ tg) {
  int i = blockIdx.x, b = blockIdx.y, j = threadIdx.x;
  __shared__ float sscale[C2], sshift[C2], swd[HH*C2];
  const float inv = 1.f / (float)(BB*NN);
  for (int c = j; c < C2; c += 192) {
    float mean = STAT2[c] * inv;
    float var  = STAT2[C2 + c] * inv - mean*mean;
    float rstd = rsqrtf(var + EPS);
    float sc = rstd * g[c];
    sscale[c] = sc;
    sshift[c] = bb[c] - mean*sc;
  }
  for (int idx = j; idx < HH*C2; idx += 192) swd[idx] = wd[idx];
  __syncthreads();
  float gacc[HH] = {};
  for (int cu = 0; cu < 32; cu++) {     // 8 channels per iter
    Pack8 p;
    #pragma unroll
    for (int e = 0; e < 8; e++) {
      int c = cu*8 + e;
      float v = raw[((size_t)(b*C2 + c))*NN + i*NP + j];
      v = fmaxf(fmaf(v, sscale[c], sshift[c]), 0.f);
      if (WRITE_NEXT) {
        float nv = v + ((c < DIM) ? CLn[(b*DIM + c)*NP + i] : CLn[(b*DIM + c - DIM)*NP + j]);
        p.h[e] = (__bf16)nv;
      }
      #pragma unroll
      for (int h = 0; h < HH; h++) gacc[h] = fmaf(v, swd[h*C2 + c], gacc[h]);
    }
    if (WRITE_NEXT) {
      size_t unit = (((size_t)(b*16 + (cu>>1))*192 + i)*2 + (cu&1))*192 + j;
      ((uint4*)inb_next)[unit] = p.u;
    }
  }
  for (int h = 0; h < HH; h++)
    tg[((size_t)(b*HH + h)*NP + i)*NP + j] = gacc[h];
}

// ---------------- gate = sigmoid(t + t^T + bias); also zero STAT2 for next layer ----------------
__global__ void k_gate_sym(const float* __restrict__ tg, const float* __restrict__ wdb,
                           float* __restrict__ gate, float* __restrict__ STAT2) {
  int i = blockIdx.x, h = blockIdx.y, b = blockIdx.z, j = threadIdx.x;
  if (blockIdx.x == 0 && blockIdx.y == 0 && blockIdx.z == 0)
    for (int s = j; s < 2*C2; s += 192) STAT2[s] = 0.f;
  size_t bh = (size_t)(b*HH + h);
  float v = tg[(bh*NP + i)*NP + j] + tg[(bh*NP + j)*NP + i] + wdb[h];
  gate[(bh*NP + i)*NP + j] = 1.f / (1.f + expf(-v));
}

// ---------------- q,k,v = heads(relu(x @ w^T + b)) ----------------
__global__ void k_qkv(const float* __restrict__ X,
                      const float* __restrict__ wq, const float* __restrict__ bq,
                      const float* __restrict__ wk, const float* __restrict__ bk,
                      const float* __restrict__ wv, const float* __restrict__ bv,
                      float* __restrict__ Q, float* __restrict__ K, float* __restrict__ V) {
  int t = blockIdx.x, b = blockIdx.y, d = threadIdx.x;
  __shared__ float sy[DIM];
  sy[d] = X[(b*NP + t)*DIM + d];
  __syncthreads();
  float aq = bq[d], ak = bk[d], av = bv[d];
  for (int e = 0; e < DIM; e++) {
    float xv = sy[e];
    aq = fmaf(wq[d*DIM + e], xv, aq);
    ak = fmaf(wk[d*DIM + e], xv, ak);
    av = fmaf(wv[d*DIM + e], xv, av);
  }
  int h = d >> 4, dh = d & 15;
  size_t o = ((size_t)(b*HH + h)*NP + t)*DHH + dh;
  Q[o] = fmaxf(aq, 0.f); K[o] = fmaxf(ak, 0.f); V[o] = fmaxf(av, 0.f);
}

// ---------------- attention row ----------------
__global__ void k_attn(const float* __restrict__ Q, const float* __restrict__ K,
                       const float* __restrict__ V, const float* __restrict__ gate,
                       const float* __restrict__ mask, float* __restrict__ upd) {
  int i = blockIdx.x, h = blockIdx.y, b = blockIdx.z, j = threadIdx.x;
  size_t bh = (size_t)(b*HH + h);
  __shared__ float sq[DHH];
  __shared__ float sb[NP];
  __shared__ float sattn[NP];
  if (j < DHH) sq[j] = Q[(bh*NP + i)*DHH + j];
  __syncthreads();
  const float* kr = K + (bh*NP + j)*DHH;
  float a = 0.f;
  #pragma unroll
  for (int d = 0; d < DHH; d++) a = fmaf(sq[d], kr[d], a);
  a *= 0.25f;
  sb[j] = a; __syncthreads();
  for (int s = 128; s > 0; s >>= 1) {
    if (j < s && j + s < NP) sb[j] = fmaxf(sb[j], sb[j+s]);
    __syncthreads();
  }
  float amax = sb[0];
  __syncthreads();
  float e = expf(a - amax) * mask[b*NP + j];
  sb[j] = e; __syncthreads();
  for (int s = 128; s > 0; s >>= 1) {
    if (j < s && j + s < NP) sb[j] += sb[j+s];
    __syncthreads();
  }
  float denom = sb[0] + 1e-6f;
  float attn = (e / denom) * gate[(bh*NP + i)*NP + j];
  sattn[j] = attn;
  __syncthreads();
  if (j < DHH) {
    float acc = 0.f;
    for (int jj = 0; jj < NP; jj++)
      acc = fmaf(sattn[jj], V[(bh*NP + jj)*DHH + j], acc);
    upd[((size_t)(b*NP) + i)*DIM + h*DHH + j] = acc;
  }
}

// ---------------- x = relu((x + upd) @ wl^T + bl) ----------------
__global__ void k_xup(float* __restrict__ X, const float* __restrict__ upd,
                      const float* __restrict__ wl, const float* __restrict__ bl) {
  int t = blockIdx.x, b = blockIdx.y, d = threadIdx.x;
  __shared__ float sy[DIM];
  size_t o = (size_t)(b*NP + t)*DIM;
  sy[d] = X[o + d] + upd[o + d];
  __syncthreads();
  float acc = bl[d];
  for (int e = 0; e < DIM; e++) acc = fmaf(wl[d*DIM + e], sy[e], acc);
  X[o + d] = fmaxf(acc, 0.f);
}

// ---------------- out = relu(x @ fc^T + fb) ----------------
__global__ void k_final(const float* __restrict__ X, const float* __restrict__ fc,
                        const float* __restrict__ fb, float* __restrict__ out) {
  int t = blockIdx.x, b = blockIdx.y, d = threadIdx.x;
  __shared__ float sy[DIM];
  size_t o = (size_t)(b*NP + t)*DIM;
  sy[d] = X[o + d];
  __syncthreads();
  float acc = fb[d];
  for (int e = 0; e < DIM; e++) acc = fmaf(fc[d*DIM + e], sy[e], acc);
  out[o + d] = fmaxf(acc, 0.f);
}

extern "C" void kernel_launch(void* const* d_in, const int* in_sizes, int n_in,
                              void* d_out, int out_size, void* d_ws, size_t ws_size,
                              hipStream_t stream) {
  const float* seq     = (const float*)d_in[0];
  const float* mask    = (const float*)d_in[1];
  const float* conv1_w = (const float*)d_in[2];
  const float* conv2_w = (const float*)d_in[3];
  const float* ln_g    = (const float*)d_in[4];
  const float* ln_b    = (const float*)d_in[5];
  const float* c1d_w   = (const float*)d_in[6];
  const float* bn1_g   = (const float*)d_in[7];
  const float* bn1_b   = (const float*)d_in[8];
  const float* c2d_w   = (const float*)d_in[9];
  const float* bn2_g   = (const float*)d_in[10];
  const float* bn2_b   = (const float*)d_in[11];
  const float* wq_w    = (const float*)d_in[12];
  const float* wq_b    = (const float*)d_in[13];
  const float* wk_w    = (const float*)d_in[14];
  const float* wk_b    = (const float*)d_in[15];
  const float* wv_w    = (const float*)d_in[16];
  const float* wv_b    = (const float*)d_in[17];
  const float* wd_w    = (const float*)d_in[18];
  const float* wd_b    = (const float*)d_in[19];
  const float* wl_w    = (const float*)d_in[20];
  const float* wl_b    = (const float*)d_in[21];
  const float* fc_w    = (const float*)d_in[22];
  const float* fc_b    = (const float*)d_in[23];
  float* out = (float*)d_out;

  float* ws = (float*)d_ws;
  float* X    = ws; ws += BB*NP*DIM;
  float* Cc   = ws; ws += BB*DIM*NP;
  float* CL0  = ws; ws += BB*DIM*NP;
  float* CL1  = ws; ws += BB*DIM*NP;
  float* CL2  = ws; ws += BB*DIM*NP;
  float* Q    = ws; ws += BB*NP*DIM;
  float* K    = ws; ws += BB*NP*DIM;
  float* V    = ws; ws += BB*NP*DIM;
  float* UPD  = ws; ws += BB*NP*DIM;
  float* TG   = ws; ws += (size_t)BB*HH*NN;
  float* GATE = ws; ws += (size_t)BB*HH*NN;
  float* STAT2= ws; ws += 2*C2;
  float* C2B  = ws; ws += (size_t)BB*C2*NN;            // raw conv output fp32
  __bf16* INB = (__bf16*)ws; ws += (size_t)BB*C2*NN/2; // conv input bf16
  __bf16* WTB = (__bf16*)ws; ws += (size_t)LL*C2*C2*9/2;

  const float* CL[3] = {CL0, CL1, CL2};

  // weight prep (all 3 layers) + init convs + conv1d chain (independent of c2/x loop)
  k_wprep<<<LL*16*9, 512, 0, stream>>>(c2d_w, WTB);
  k_conv_init<<<dim3(NP, BB), DIM, 0, stream>>>(seq, conv1_w, conv2_w, X, Cc);
  k_conv1d_bn_relu<<<DIM, NP, 0, stream>>>(Cc,  c1d_w + 0*(size_t)DIM*DIM*3, bn1_g + 0*DIM, bn1_b + 0*DIM, CL0);
  k_conv1d_bn_relu<<<DIM, NP, 0, stream>>>(CL0, c1d_w + 1*(size_t)DIM*DIM*3, bn1_g + 1*DIM, bn1_b + 1*DIM, CL1);
  k_conv1d_bn_relu<<<DIM, NP, 0, stream>>>(CL1, c1d_w + 2*(size_t)DIM*DIM*3, bn1_g + 2*DIM, bn1_b + 2*DIM, CL2);
  // layer-0 conv input (also zeroes STAT2)
  k_make_convin<<<(BB*16*NP*2*NP)/256, 256, 0, stream>>>(Cc, CL0, INB, STAT2);

  for (int l = 0; l < LL; l++) {
    k_add_ln<<<dim3(NP, BB), DIM, 0, stream>>>(X, CL[l], ln_g + l*DIM, ln_b + l*DIM);
    k_conv2d_mfma<<<dim3(3, 48, 4), 256, 0, stream>>>(INB, WTB + (size_t)l*16*9*2*256*8, C2B);
    k_bn2_stats4<<<dim3(C2, 4), 256, 0, stream>>>(C2B, STAT2);
    if (l < LL-1)
      k_bn2_norm_gate<1><<<dim3(NP, BB), NP, 0, stream>>>(C2B, STAT2, bn2_g + l*C2, bn2_b + l*C2,
                                                          wd_w + (size_t)l*HH*C2, CL[l+1], INB, TG);
    else
      k_bn2_norm_gate<0><<<dim3(NP, BB), NP, 0, stream>>>(C2B, STAT2, bn2_g + l*C2, bn2_b + l*C2,
                                                          wd_w + (size_t)l*HH*C2, nullptr, nullptr, TG);
    k_gate_sym<<<dim3(NP, HH, BB), NP, 0, stream>>>(TG, wd_b + l*HH, GATE, STAT2);
    k_qkv<<<dim3(NP, BB), DIM, 0, stream>>>(X, wq_w + (size_t)l*DIM*DIM, wq_b + l*DIM,
                                            wk_w + (size_t)l*DIM*DIM, wk_b + l*DIM,
                                            wv_w + (size_t)l*DIM*DIM, wv_b + l*DIM, Q, K, V);
    k_attn<<<dim3(NP, HH, BB), NP, 0, stream>>>(Q, K, V, GATE, mask, UPD);
    k_xup<<<dim3(NP, BB), DIM, 0, stream>>>(X, UPD, wl_w + (size_t)l*DIM*DIM, wl_b + l*DIM);
  }
  k_final<<<dim3(NP, BB), DIM, 0, stream>>>(X, fc_w, fc_b, out);
}

// Round 3
// 984.034 us; speedup vs baseline: 4.9593x; 1.0261x over previous
//
#include <hip/hip_runtime.h>
#include <math.h>

#define IN_DIM 20
#define DIM 128
#define HH 8
#define LL 3
#define BB 2
#define NP 192
#define DHH 16
#define C2 256
#define NN (NP*NP)
#define EPS 1e-5f

typedef __bf16 bf16x8 __attribute__((ext_vector_type(8)));
typedef float  f32x16 __attribute__((ext_vector_type(16)));

union Pack8 { __bf16 h[8]; uint4 u; };

// ---------------- init: conv1d over seq for both x and c ----------------
__global__ void k_conv_init(const float* __restrict__ seq, const float* __restrict__ w1,
                            const float* __restrict__ w2, float* __restrict__ X,
                            float* __restrict__ Cc) {
  int t = blockIdx.x, b = blockIdx.y, oc = threadIdx.x;
  __shared__ float ss[3][IN_DIM];
  if (threadIdx.x < 3*IN_DIM) {
    int k = threadIdx.x / IN_DIM, ic = threadIdx.x % IN_DIM;
    int tt = t + k - 1;
    ss[k][ic] = (tt >= 0 && tt < NP) ? seq[(b*NP + tt)*IN_DIM + ic] : 0.f;
  }
  __syncthreads();
  float a1 = 0.f, a2 = 0.f;
  #pragma unroll
  for (int ic = 0; ic < IN_DIM; ic++) {
    #pragma unroll
    for (int k = 0; k < 3; k++) {
      float sv = ss[k][ic];
      a1 = fmaf(w1[(oc*IN_DIM + ic)*3 + k], sv, a1);
      a2 = fmaf(w2[(oc*IN_DIM + ic)*3 + k], sv, a2);
    }
  }
  X[(b*NP + t)*DIM + oc] = a1;
  Cc[(b*DIM + oc)*NP + t] = a2;
}

// ---------------- conv1d + BN(train stats) + relu, fused ----------------
__global__ void k_conv1d_bn_relu(const float* __restrict__ cin, const float* __restrict__ w,
                                 const float* __restrict__ g, const float* __restrict__ bb,
                                 float* __restrict__ cout) {
  int oc = blockIdx.x;
  int t = threadIdx.x;
  float raw[BB];
  for (int b = 0; b < BB; b++) {
    float acc = 0.f;
    for (int ic = 0; ic < DIM; ic++) {
      const float* cr = cin + (b*DIM + ic)*NP;
      const float* wr = w + (oc*DIM + ic)*3;
      float lf = (t > 0)      ? cr[t-1] : 0.f;
      float mf = cr[t];
      float rf = (t < NP-1)   ? cr[t+1] : 0.f;
      acc = fmaf(lf, wr[0], acc);
      acc = fmaf(mf, wr[1], acc);
      acc = fmaf(rf, wr[2], acc);
    }
    raw[b] = acc;
  }
  __shared__ float sb[NP];
  sb[t] = raw[0] + raw[1];
  __syncthreads();
  for (int s = 128; s > 0; s >>= 1) {
    if (t < s && t + s < NP) sb[t] += sb[t + s];
    __syncthreads();
  }
  float mean = sb[0] / (float)(BB*NP);
  __syncthreads();
  sb[t] = raw[0]*raw[0] + raw[1]*raw[1];
  __syncthreads();
  for (int s = 128; s > 0; s >>= 1) {
    if (t < s && t + s < NP) sb[t] += sb[t + s];
    __syncthreads();
  }
  float var = sb[0] / (float)(BB*NP) - mean*mean;
  float rstd = rsqrtf(var + EPS);
  float gg = g[oc], bo = bb[oc];
  for (int b = 0; b < BB; b++)
    cout[(b*DIM + oc)*NP + t] = fmaxf((raw[b] - mean)*rstd*gg + bo, 0.f);
}

// ---------------- fused: x = LN(x + c^T), then q,k,v = heads(relu(x@w^T+b)) ----------------
// grid (NP, BB), block DIM
__global__ void k_lnqkv(float* __restrict__ X, const float* __restrict__ cc,
                        const float* __restrict__ g, const float* __restrict__ bb,
                        const float* __restrict__ wq, const float* __restrict__ bq,
                        const float* __restrict__ wk, const float* __restrict__ bk,
                        const float* __restrict__ wv, const float* __restrict__ bv,
                        float* __restrict__ Q, float* __restrict__ K, float* __restrict__ V) {
  int t = blockIdx.x, b = blockIdx.y, d = threadIdx.x;
  __shared__ float sb[DIM];
  __shared__ float sy[DIM];
  float v = X[(b*NP + t)*DIM + d] + cc[(b*DIM + d)*NP + t];
  sb[d] = v; __syncthreads();
  for (int s = 64; s > 0; s >>= 1) { if (d < s) sb[d] += sb[d+s]; __syncthreads(); }
  float mean = sb[0] / (float)DIM;
  __syncthreads();
  float dv = v - mean;
  sb[d] = dv*dv; __syncthreads();
  for (int s = 64; s > 0; s >>= 1) { if (d < s) sb[d] += sb[d+s]; __syncthreads(); }
  float var = sb[0] / (float)DIM;
  float rstd = rsqrtf(var + EPS);
  float xn = dv * rstd * g[d] + bb[d];
  X[(b*NP + t)*DIM + d] = xn;
  sy[d] = xn;
  __syncthreads();
  float aq = bq[d], ak = bk[d], av = bv[d];
  for (int e = 0; e < DIM; e++) {
    float xv = sy[e];
    aq = fmaf(wq[d*DIM + e], xv, aq);
    ak = fmaf(wk[d*DIM + e], xv, ak);
    av = fmaf(wv[d*DIM + e], xv, av);
  }
  int h = d >> 4, dh = d & 15;
  size_t o = ((size_t)(b*HH + h)*NP + t)*DHH + dh;
  Q[o] = fmaxf(aq, 0.f); K[o] = fmaxf(ak, 0.f); V[o] = fmaxf(av, 0.f);
}

// ---------------- conv2d weight prep: fp32 [L][oc][ic][3][3] -> bf16 [L][chunk16][kk9][kh2][oc256][8] ----------------
__global__ void k_wprep(const float* __restrict__ w, __bf16* __restrict__ wtb) {
  int blk = blockIdx.x;            // 3*16*9
  int kk = blk % 9;
  int chunk = (blk / 9) % 16;
  int l = blk / (9*16);
  int kh = threadIdx.x >> 8;
  int oc = threadIdx.x & 255;
  Pack8 p;
  #pragma unroll
  for (int e = 0; e < 8; e++) {
    int ic = chunk*16 + kh*8 + e;
    p.h[e] = (__bf16)w[(((size_t)(l*C2 + oc))*C2 + ic)*9 + kk];
  }
  size_t unit = ((((size_t)(l*16 + chunk)*9 + kk)*2 + kh)*256 + oc);
  ((uint4*)wtb)[unit] = p.u;
}

// ---------------- layer-0 conv input build: bf16(seq2pair(Cc) + seq2pair(CL0)); zeroes STAT2 ----------------
__global__ void k_make_convin(const float* __restrict__ Cc, const float* __restrict__ CL0,
                              __bf16* __restrict__ inb, float* __restrict__ STAT2) {
  int idx = blockIdx.x*256 + threadIdx.x;   // (b,chunk,i,kh,j) units
  if (blockIdx.x == 0 && threadIdx.x < 256) {
    STAT2[threadIdx.x] = 0.f; STAT2[256 + threadIdx.x] = 0.f;
  }
  int j = idx % 192;
  int r1 = idx / 192;
  int kh = r1 & 1;
  int r2 = r1 >> 1;
  int i = r2 % 192;
  int r3 = r2 / 192;
  int chunk = r3 % 16;
  int b = r3 / 16;
  Pack8 p;
  #pragma unroll
  for (int e = 0; e < 8; e++) {
    int c = chunk*16 + kh*8 + e;
    float v;
    if (c < DIM) v = Cc[(b*DIM + c)*NP + i] + CL0[(b*DIM + c)*NP + i];
    else { int cc = c - DIM; v = Cc[(b*DIM + cc)*NP + j] + CL0[(b*DIM + cc)*NP + j]; }
    p.h[e] = (__bf16)v;
  }
  ((uint4*)inb)[idx] = p.u;
}

// ---------------- the heavy kernel: implicit-GEMM bf16 MFMA 3x3 conv, bf16 packed output ----------------
// grid (3 jt, 48 it, 4 = b*2+oct), block 256 (4 waves)
// output layout: [b][G=c/8][i][j][8c] 16B units
__global__ __launch_bounds__(256, 2)
void k_conv2d_mfma(const __bf16* __restrict__ inb,   // [b][16][192][2][192][8]
                   const __bf16* __restrict__ wtb,   // [16][9][2][256][8] (layer slice)
                   __bf16* __restrict__ rawb) {      // [b][32][192][192][8]
  __shared__ __align__(16) __bf16 sW[9*2*128*8];     // 36864 B
  __shared__ __align__(16) __bf16 sI[6*2*80*8];      // 15360 B
  __shared__ __align__(16) float  sT[4*32*33];       // 16896 B, per-wave transpose buf
  int tid = threadIdx.x;
  int jt = blockIdx.x, it = blockIdx.y, zz = blockIdx.z;
  int b = zz >> 1, oct = zz & 1;
  int i0 = it*4, j0 = jt*64, oc0 = oct*128;
  int lane = tid & 63, wv = tid >> 6;
  int wm = wv & 1, wn = wv >> 1;
  int ln31 = lane & 31, kh = lane >> 5;

  const uint4* gW = (const uint4*)wtb;
  const uint4* gI = (const uint4*)inb;
  uint4* lW = (uint4*)sW;
  uint4* lI = (uint4*)sI;

  f32x16 acc[2][4];
  #pragma unroll
  for (int m = 0; m < 2; m++)
    #pragma unroll
    for (int n = 0; n < 4; n++)
      #pragma unroll
      for (int q = 0; q < 16; q++) acc[m][n][q] = 0.f;

  uint4 wreg[9], ireg[4];

  auto load_w = [&](int chunk) {
    #pragma unroll
    for (int t = 0; t < 9; t++) {
      int u = t*256 + tid;
      int kkh = u >> 7, oc_l = u & 127;
      wreg[t] = gW[((size_t)chunk*18 + kkh)*256 + oc0 + oc_l];
    }
  };
  auto load_i = [&](int chunk) {
    #pragma unroll
    for (int t = 0; t < 4; t++) {
      int u = t*256 + tid;
      uint4 v; v.x = v.y = v.z = v.w = 0u;
      if (u < 960) {
        int r = u / 160, rem = u % 160;
        int khu = rem / 80, cc = rem % 80;
        int row = i0 - 1 + r;
        int cj = j0 - 8 + cc;
        if ((unsigned)row < 192u && (unsigned)cj < 192u)
          v = gI[(((size_t)(b*16 + chunk)*192 + row)*2 + khu)*192 + cj];
      }
      ireg[t] = v;
    }
  };

  load_w(0); load_i(0);

  for (int chunk = 0; chunk < 16; ++chunk) {
    if (chunk) __syncthreads();
    #pragma unroll
    for (int t = 0; t < 9; t++) lW[t*256 + tid] = wreg[t];
    #pragma unroll
    for (int t = 0; t < 4; t++) {
      int u = t*256 + tid;
      if (u < 960) {
        int r = u / 160, rem = u % 160;
        int khu = rem / 80, cc = rem % 80;
        lI[(r*2 + khu)*80 + cc] = ireg[t];
      }
    }
    if (chunk < 15) { load_w(chunk+1); load_i(chunk+1); }
    __syncthreads();

    #pragma unroll
    for (int kk = 0; kk < 9; kk++) {
      const int ki = kk/3, kj = kk%3;
      bf16x8 a0 = *(const bf16x8*)(sW + (((kk*2 + kh)*128) + wm*64 +      ln31)*8);
      bf16x8 a1 = *(const bf16x8*)(sW + (((kk*2 + kh)*128) + wm*64 + 32 + ln31)*8);
      #pragma unroll
      for (int nt = 0; nt < 4; nt++) {
        int r  = wn*2 + (nt>>1) + ki;
        int cc = (nt&1)*32 + ln31 + kj + 7;
        bf16x8 bv = *(const bf16x8*)(sI + ((r*2 + kh)*80 + cc)*8);
        acc[0][nt] = __builtin_amdgcn_mfma_f32_32x32x16_bf16(a0, bv, acc[0][nt], 0, 0, 0);
        acc[1][nt] = __builtin_amdgcn_mfma_f32_32x32x16_bf16(a1, bv, acc[1][nt], 0, 0, 0);
      }
    }
  }

  // epilogue: per-wave LDS transpose of each 32ch x 32jj tile -> packed bf16 16B stores
  float* tr = sT + wv*(32*33);
  uint4* RAWu = (uint4*)rawb;
  #pragma unroll
  for (int mt = 0; mt < 2; mt++) {
    int cbase = oc0 + wm*64 + mt*32;
    int Gb = cbase >> 3;
    #pragma unroll
    for (int nt = 0; nt < 4; nt++) {
      int ii = i0 + wn*2 + (nt>>1);
      int jb = j0 + (nt&1)*32;
      __syncthreads();
      #pragma unroll
      for (int reg = 0; reg < 16; reg++) {
        int row = (reg & 3) + 8*(reg >> 2) + 4*kh;
        tr[row*33 + ln31] = acc[mt][nt][reg];
      }
      __syncthreads();
      #pragma unroll
      for (int gs = 0; gs < 2; gs++) {
        int g = kh + gs*2;
        Pack8 p;
        #pragma unroll
        for (int e = 0; e < 8; e++) p.h[e] = (__bf16)tr[(g*8 + e)*33 + ln31];
        RAWu[(((size_t)(b*32 + Gb + g)*192) + ii)*192 + jb + ln31] = p.u;
      }
    }
  }
}

// ---------------- BN2 stats on packed bf16: grid (32, BB*4), atomics into STAT2 ----------------
__global__ void k_bn2_stats(const __bf16* __restrict__ rawb, float* __restrict__ STAT2) {
  int G = blockIdx.x;
  int b = blockIdx.y >> 2, q = blockIdx.y & 3;
  int tid = threadIdx.x;
  const uint4* p = (const uint4*)rawb + (size_t)(b*32 + G)*NN + q*(NN/4);
  float s[8] = {}, s2[8] = {};
  for (int k = 0; k < (NN/4)/256; k++) {
    Pack8 pk; pk.u = p[k*256 + tid];
    #pragma unroll
    for (int e = 0; e < 8; e++) { float v = (float)pk.h[e]; s[e] += v; s2[e] = fmaf(v, v, s2[e]); }
  }
  #pragma unroll
  for (int m = 32; m >= 1; m >>= 1) {
    #pragma unroll
    for (int e = 0; e < 8; e++) {
      s[e]  += __shfl_xor(s[e],  m);
      s2[e] += __shfl_xor(s2[e], m);
    }
  }
  if ((tid & 63) == 0) {
    #pragma unroll
    for (int e = 0; e < 8; e++) {
      atomicAdd(&STAT2[G*8 + e], s[e]);
      atomicAdd(&STAT2[C2 + G*8 + e], s2[e]);
    }
  }
}

// ---------------- fused: BN2 norm+relu, gate projection, next conv input bf16 ----------------
// grid (192, 2), block 192
template<int WRITE_NEXT>
__global__ void k_bn2_norm_gate(const __bf16* __restrict__ rawb, const float* __restrict__ STAT2,
                                const float* __restrict__ g, const float* __restrict__ bb,
                                const float* __restrict__ wd, const float* __restrict__ CLn,
                                __bf16* __restrict__ inb_next, float* __restrict__ tg) {
  int i = blockIdx.x, b = blockIdx.y, j = threadIdx.x;
  __shared__ float sscale[C2], sshift[C2], swd[HH*C2];
  const float inv = 1.f / (float)(BB*NN);
  for (int c = j; c < C2; c += 192) {
    float mean = STAT2[c] * inv;
    float var  = STAT2[C2 + c] * inv - mean*mean;
    float rstd = rsqrtf(var + EPS);
    float sc = rstd * g[c];
    sscale[c] = sc;
    sshift[c] = bb[c] - mean*sc;
  }
  for (int idx = j; idx < HH*C2; idx += 192) swd[idx] = wd[idx];
  __syncthreads();
  float gacc[HH] = {};
  const uint4* RAWu = (const uint4*)rawb;
  for (int cu = 0; cu < 32; cu++) {
    Pack8 pr; pr.u = RAWu[((size_t)(b*32 + cu)*NP + i)*NP + j];
    Pack8 p;
    #pragma unroll
    for (int e = 0; e < 8; e++) {
      int c = cu*8 + e;
      float v = (float)pr.h[e];
      v = fmaxf(fmaf(v, sscale[c], sshift[c]), 0.f);
      if (WRITE_NEXT) {
        float nv = v + ((c < DIM) ? CLn[(b*DIM + c)*NP + i] : CLn[(b*DIM + c - DIM)*NP + j]);
        p.h[e] = (__bf16)nv;
      }
      #pragma unroll
      for (int h = 0; h < HH; h++) gacc[h] = fmaf(v, swd[h*C2 + c], gacc[h]);
    }
    if (WRITE_NEXT) {
      size_t unit = (((size_t)(b*16 + (cu>>1))*192 + i)*2 + (cu&1))*192 + j;
      ((uint4*)inb_next)[unit] = p.u;
    }
  }
  for (int h = 0; h < HH; h++)
    tg[((size_t)(b*HH + h)*NP + i)*NP + j] = gacc[h];
}

// ---------------- attention row with inline gate=sigmoid(t+t^T+bias); zeroes STAT2 ----------------
__global__ void k_attn(const float* __restrict__ Q, const float* __restrict__ K,
                       const float* __restrict__ V, const float* __restrict__ tg,
                       const float* __restrict__ wdb, const float* __restrict__ mask,
                       float* __restrict__ upd, float* __restrict__ STAT2) {
  int i = blockIdx.x, h = blockIdx.y, b = blockIdx.z, j = threadIdx.x;
  if (i == 0 && h == 0 && b == 0)
    for (int s = j; s < 2*C2; s += 192) STAT2[s] = 0.f;
  size_t bh = (size_t)(b*HH + h);
  __shared__ float sq[DHH];
  __shared__ float sb[NP];
  __shared__ float sattn[NP];
  if (j < DHH) sq[j] = Q[(bh*NP + i)*DHH + j];
  __syncthreads();
  const float* kr = K + (bh*NP + j)*DHH;
  float a = 0.f;
  #pragma unroll
  for (int d = 0; d < DHH; d++) a = fmaf(sq[d], kr[d], a);
  a *= 0.25f;
  sb[j] = a; __syncthreads();
  for (int s = 128; s > 0; s >>= 1) {
    if (j < s && j + s < NP) sb[j] = fmaxf(sb[j], sb[j+s]);
    __syncthreads();
  }
  float amax = sb[0];
  __syncthreads();
  float e = expf(a - amax) * mask[b*NP + j];
  sb[j] = e; __syncthreads();
  for (int s = 128; s > 0; s >>= 1) {
    if (j < s && j + s < NP) sb[j] += sb[j+s];
    __syncthreads();
  }
  float denom = sb[0] + 1e-6f;
  float gv = tg[(bh*NP + i)*NP + j] + tg[(bh*NP + j)*NP + i] + wdb[h];
  float gate = 1.f / (1.f + expf(-gv));
  float attn = (e / denom) * gate;
  sattn[j] = attn;
  __syncthreads();
  if (j < DHH) {
    float acc = 0.f;
    for (int jj = 0; jj < NP; jj++)
      acc = fmaf(sattn[jj], V[(bh*NP + jj)*DHH + j], acc);
    upd[((size_t)(b*NP) + i)*DIM + h*DHH + j] = acc;
  }
}

// ---------------- x = relu((x + upd) @ wl^T + bl) ----------------
__global__ void k_xup(float* __restrict__ X, const float* __restrict__ upd,
                      const float* __restrict__ wl, const float* __restrict__ bl) {
  int t = blockIdx.x, b = blockIdx.y, d = threadIdx.x;
  __shared__ float sy[DIM];
  size_t o = (size_t)(b*NP + t)*DIM;
  sy[d] = X[o + d] + upd[o + d];
  __syncthreads();
  float acc = bl[d];
  for (int e = 0; e < DIM; e++) acc = fmaf(wl[d*DIM + e], sy[e], acc);
  X[o + d] = fmaxf(acc, 0.f);
}

// ---------------- out = relu(x @ fc^T + fb) ----------------
__global__ void k_final(const float* __restrict__ X, const float* __restrict__ fc,
                        const float* __restrict__ fb, float* __restrict__ out) {
  int t = blockIdx.x, b = blockIdx.y, d = threadIdx.x;
  __shared__ float sy[DIM];
  size_t o = (size_t)(b*NP + t)*DIM;
  sy[d] = X[o + d];
  __syncthreads();
  float acc = fb[d];
  for (int e = 0; e < DIM; e++) acc = fmaf(fc[d*DIM + e], sy[e], acc);
  out[o + d] = fmaxf(acc, 0.f);
}

extern "C" void kernel_launch(void* const* d_in, const int* in_sizes, int n_in,
                              void* d_out, int out_size, void* d_ws, size_t ws_size,
                              hipStream_t stream) {
  const float* seq     = (const float*)d_in[0];
  const float* mask    = (const float*)d_in[1];
  const float* conv1_w = (const float*)d_in[2];
  const float* conv2_w = (const float*)d_in[3];
  const float* ln_g    = (const float*)d_in[4];
  const float* ln_b    = (const float*)d_in[5];
  const float* c1d_w   = (const float*)d_in[6];
  const float* bn1_g   = (const float*)d_in[7];
  const float* bn1_b   = (const float*)d_in[8];
  const float* c2d_w   = (const float*)d_in[9];
  const float* bn2_g   = (const float*)d_in[10];
  const float* bn2_b   = (const float*)d_in[11];
  const float* wq_w    = (const float*)d_in[12];
  const float* wq_b    = (const float*)d_in[13];
  const float* wk_w    = (const float*)d_in[14];
  const float* wk_b    = (const float*)d_in[15];
  const float* wv_w    = (const float*)d_in[16];
  const float* wv_b    = (const float*)d_in[17];
  const float* wd_w    = (const float*)d_in[18];
  const float* wd_b    = (const float*)d_in[19];
  const float* wl_w    = (const float*)d_in[20];
  const float* wl_b    = (const float*)d_in[21];
  const float* fc_w    = (const float*)d_in[22];
  const float* fc_b    = (const float*)d_in[23];
  float* out = (float*)d_out;

  float* ws = (float*)d_ws;
  float* X    = ws; ws += BB*NP*DIM;
  float* Cc   = ws; ws += BB*DIM*NP;
  float* CL0  = ws; ws += BB*DIM*NP;
  float* CL1  = ws; ws += BB*DIM*NP;
  float* CL2  = ws; ws += BB*DIM*NP;
  float* Q    = ws; ws += BB*NP*DIM;
  float* K    = ws; ws += BB*NP*DIM;
  float* V    = ws; ws += BB*NP*DIM;
  float* UPD  = ws; ws += BB*NP*DIM;
  float* TG   = ws; ws += (size_t)BB*HH*NN;
  float* STAT2= ws; ws += 2*C2;
  __bf16* RAW = (__bf16*)ws; ws += (size_t)BB*C2*NN/2;  // raw conv output, packed bf16
  __bf16* INB = (__bf16*)ws; ws += (size_t)BB*C2*NN/2;  // conv input bf16
  __bf16* WTB = (__bf16*)ws; ws += (size_t)LL*C2*C2*9/2;

  const float* CL[3] = {CL0, CL1, CL2};

  k_wprep<<<LL*16*9, 512, 0, stream>>>(c2d_w, WTB);
  k_conv_init<<<dim3(NP, BB), DIM, 0, stream>>>(seq, conv1_w, conv2_w, X, Cc);
  k_conv1d_bn_relu<<<DIM, NP, 0, stream>>>(Cc,  c1d_w + 0*(size_t)DIM*DIM*3, bn1_g + 0*DIM, bn1_b + 0*DIM, CL0);
  k_conv1d_bn_relu<<<DIM, NP, 0, stream>>>(CL0, c1d_w + 1*(size_t)DIM*DIM*3, bn1_g + 1*DIM, bn1_b + 1*DIM, CL1);
  k_conv1d_bn_relu<<<DIM, NP, 0, stream>>>(CL1, c1d_w + 2*(size_t)DIM*DIM*3, bn1_g + 2*DIM, bn1_b + 2*DIM, CL2);
  k_make_convin<<<(BB*16*NP*2*NP)/256, 256, 0, stream>>>(Cc, CL0, INB, STAT2);

  for (int l = 0; l < LL; l++) {
    k_lnqkv<<<dim3(NP, BB), DIM, 0, stream>>>(X, CL[l], ln_g + l*DIM, ln_b + l*DIM,
                                              wq_w + (size_t)l*DIM*DIM, wq_b + l*DIM,
                                              wk_w + (size_t)l*DIM*DIM, wk_b + l*DIM,
                                              wv_w + (size_t)l*DIM*DIM, wv_b + l*DIM, Q, K, V);
    k_conv2d_mfma<<<dim3(3, 48, 4), 256, 0, stream>>>(INB, WTB + (size_t)l*16*9*2*256*8, RAW);
    k_bn2_stats<<<dim3(32, BB*4), 256, 0, stream>>>(RAW, STAT2);
    if (l < LL-1)
      k_bn2_norm_gate<1><<<dim3(NP, BB), NP, 0, stream>>>(RAW, STAT2, bn2_g + l*C2, bn2_b + l*C2,
                                                          wd_w + (size_t)l*HH*C2, CL[l+1], INB, TG);
    else
      k_bn2_norm_gate<0><<<dim3(NP, BB), NP, 0, stream>>>(RAW, STAT2, bn2_g + l*C2, bn2_b + l*C2,
                                                          wd_w + (size_t)l*HH*C2, nullptr, nullptr, TG);
    k_attn<<<dim3(NP, HH, BB), NP, 0, stream>>>(Q, K, V, TG, wd_b + l*HH, mask, UPD, STAT2);
    k_xup<<<dim3(NP, BB), DIM, 0, stream>>>(X, UPD, wl_w + (size_t)l*DIM*DIM, wl_b + l*DIM);
  }
  k_final<<<dim3(NP, BB), DIM, 0, stream>>>(X, fc_w, fc_b, out);
}